// Round 2
// 550.272 us; speedup vs baseline: 1.0598x; 1.0598x over previous
//
#include <hip/hip_runtime.h>

// ---------------------------------------------------------------------------
// FUSED 2-layer LSTM (Keras gates i,f,g,o) + Dense(27) + softmax. fp32.
// B=32768, T=21, F=126, U=8.
//
// R6 = R5 resubmit (R5 bench died on container infra, no signal).
// Single persistent kernel, NO workspace. The previous split design paid
// (a) a 1.387 GB workspace re-poison fill (~210us) inside the timed
// region, (b) 176 MB of Z round-trip HBM traffic, (c) a second launch
// fully serialized behind the first. Phase-2 consumes Z exactly in the
// order phase-1 produces it, so fuse: per t, stage x(t) (LDS dbuf, VGPR
// prefetch of t+1 issued under t's compute), GEMM 32 gate cols (wave =
// 8 cols, lane = sample), += h1@W1r, exchange via LDS, LSTM1 update
// (replicated per wave), layer-2 small GEMM, exchange, LSTM2 update.
//
// LDS/block: 2*31.5KB (x dbuf) + 2*8KB (gate exchange) = 80,896 B
//   -> 2 blocks/CU (161,792 <= 163,840). grid=512 (=2 blocks/CU on 256 CU).
// Roofline: X read 347 MB ~ 55us; VALU ~ 45us -> expect ~80us kernel.
// ---------------------------------------------------------------------------

namespace {
constexpr int T_  = 21;
constexpr int FIN = 126;
constexpr int U_  = 8;
constexpr int NC  = 27;
constexpr int ZC  = 4 * U_;              // 32 gate columns
constexpr int ROW = T_ * FIN;            // 2646 floats per sample
}

__device__ __forceinline__ float sigm(float x) {
  return __builtin_amdgcn_rcpf(1.0f + __expf(-x));
}
__device__ __forceinline__ float tanh_f(float x) {
  return 1.0f - 2.0f * __builtin_amdgcn_rcpf(1.0f + __expf(2.0f * x));
}

__global__ __launch_bounds__(256) void lstm_fused(
    const float* __restrict__ X,
    const float* __restrict__ W1k, const float* __restrict__ b1,
    const float* __restrict__ W1r,
    const float* __restrict__ W2k, const float* __restrict__ W2r,
    const float* __restrict__ b2,
    const float* __restrict__ Wd, const float* __restrict__ bd,
    float* __restrict__ out)
{
  __shared__ __align__(16) float xb[2][64 * FIN];   // 2 x 32256 B
  __shared__ __align__(16) float zb1[ZC * 64];      // 8 KB
  __shared__ __align__(16) float zb2[ZC * 64];      // 8 KB

  const int tid = threadIdx.x;
  const int sl  = tid & 63;                                   // sample lane
  const int wv  = __builtin_amdgcn_readfirstlane(tid >> 6);   // col group
  const int grp = blockIdx.x;

  // staging index decomposition (fixed per thread across t): j over 64*63
  // float2 elements; s = row (sample), q = float2 index within 504B slice.
  int  goff[16];   // global float-offset (sans t*FIN term)
  int  loff[16];   // LDS float-offset
  bool val[16];
  #pragma unroll
  for (int k = 0; k < 16; ++k) {
    int j = tid + k * 256;
    val[k] = (j < 64 * 63);
    int s = j / 63;
    int q = j - s * 63;
    goff[k] = s * ROW + 2 * q;
    loff[k] = s * FIN + 2 * q;
  }

  const float* xbase = X + (size_t)grp * 64 * ROW;

  // wave's 8 columns: [8wv, 8wv+8)
  const float4* Wk4 = reinterpret_cast<const float4*>(W1k) + 2 * wv;
  const float4  b1a = reinterpret_cast<const float4*>(b1)[2 * wv];
  const float4  b1b = reinterpret_cast<const float4*>(b1)[2 * wv + 1];
  const float4  b2a = reinterpret_cast<const float4*>(b2)[2 * wv];
  const float4  b2b = reinterpret_cast<const float4*>(b2)[2 * wv + 1];

  float h1[U_], c1[U_], h2[U_], c2[U_];
  #pragma unroll
  for (int u = 0; u < U_; ++u) { h1[u] = 0.f; c1[u] = 0.f; h2[u] = 0.f; c2[u] = 0.f; }

  // prologue: prefetch t=0 into registers
  float2 pf[16];
  #pragma unroll
  for (int k = 0; k < 16; ++k)
    if (val[k]) pf[k] = *reinterpret_cast<const float2*>(xbase + goff[k]);

  int p = 0;
  for (int t = 0; t < T_; ++t) {
    // drain prefetch into LDS buffer p
    #pragma unroll
    for (int k = 0; k < 16; ++k)
      if (val[k]) *reinterpret_cast<float2*>(&xb[p][loff[k]]) = pf[k];
    __syncthreads();                                   // B1

    // issue prefetch for t+1 (latency covered by t's compute below)
    if (t + 1 < T_) {
      const float* xt = xbase + (t + 1) * FIN;
      #pragma unroll
      for (int k = 0; k < 16; ++k)
        if (val[k]) pf[k] = *reinterpret_cast<const float2*>(xt + goff[k]);
    }

    // ---- layer 1 GEMM: z1 = b1 + x(t) @ W1k (this wave's 8 cols) ----
    float4 za = b1a, zbv = b1b;
    const float2* xr = reinterpret_cast<const float2*>(&xb[p][sl * FIN]);
    #pragma unroll 3
    for (int q = 0; q < 63; ++q) {
      float2 xv = xr[q];
      float4 wa0 = Wk4[(2 * q) * 8];
      float4 wb0 = Wk4[(2 * q) * 8 + 1];
      float4 wa1 = Wk4[(2 * q + 1) * 8];
      float4 wb1 = Wk4[(2 * q + 1) * 8 + 1];
      za.x  = fmaf(xv.x, wa0.x, za.x);  za.y  = fmaf(xv.x, wa0.y, za.y);
      za.z  = fmaf(xv.x, wa0.z, za.z);  za.w  = fmaf(xv.x, wa0.w, za.w);
      zbv.x = fmaf(xv.x, wb0.x, zbv.x); zbv.y = fmaf(xv.x, wb0.y, zbv.y);
      zbv.z = fmaf(xv.x, wb0.z, zbv.z); zbv.w = fmaf(xv.x, wb0.w, zbv.w);
      za.x  = fmaf(xv.y, wa1.x, za.x);  za.y  = fmaf(xv.y, wa1.y, za.y);
      za.z  = fmaf(xv.y, wa1.z, za.z);  za.w  = fmaf(xv.y, wa1.w, za.w);
      zbv.x = fmaf(xv.y, wb1.x, zbv.x); zbv.y = fmaf(xv.y, wb1.y, zbv.y);
      zbv.z = fmaf(xv.y, wb1.z, zbv.z); zbv.w = fmaf(xv.y, wb1.w, zbv.w);
    }

    // + h1(t-1) @ W1r (recurrent part, h1 replicated per wave)
    #pragma unroll
    for (int k = 0; k < U_; ++k) {
      float hv = h1[k];
      const float* w = &W1r[k * ZC + 8 * wv];
      za.x  = fmaf(hv, w[0], za.x);  za.y  = fmaf(hv, w[1], za.y);
      za.z  = fmaf(hv, w[2], za.z);  za.w  = fmaf(hv, w[3], za.w);
      zbv.x = fmaf(hv, w[4], zbv.x); zbv.y = fmaf(hv, w[5], zbv.y);
      zbv.z = fmaf(hv, w[6], zbv.z); zbv.w = fmaf(hv, w[7], zbv.w);
    }

    // exchange: all 32 gate cols per sample
    {
      float* zp = &zb1[(8 * wv) * 64 + sl];
      zp[0 * 64] = za.x;  zp[1 * 64] = za.y;  zp[2 * 64] = za.z;  zp[3 * 64] = za.w;
      zp[4 * 64] = zbv.x; zp[5 * 64] = zbv.y; zp[6 * 64] = zbv.z; zp[7 * 64] = zbv.w;
    }
    __syncthreads();                                   // B2

    // ---- LSTM1 state update (replicated in every wave) ----
    #pragma unroll
    for (int u = 0; u < U_; ++u) {
      float zi = zb1[u * 64 + sl];
      float zf = zb1[(U_ + u) * 64 + sl];
      float zg = zb1[(2 * U_ + u) * 64 + sl];
      float zo = zb1[(3 * U_ + u) * 64 + sl];
      float iv = sigm(zi), fv = sigm(zf), gv = tanh_f(zg), ov = sigm(zo);
      float cn = fv * c1[u] + iv * gv;
      c1[u] = cn;
      h1[u] = ov * tanh_f(cn);
    }

    // ---- layer 2: z2 slice = b2 + h1 @ W2k + h2 @ W2r ----
    {
      float4 za2 = b2a, zb2v = b2b;
      #pragma unroll
      for (int k = 0; k < U_; ++k) {
        float hv = h1[k];
        const float* w = &W2k[k * ZC + 8 * wv];
        za2.x  = fmaf(hv, w[0], za2.x);  za2.y  = fmaf(hv, w[1], za2.y);
        za2.z  = fmaf(hv, w[2], za2.z);  za2.w  = fmaf(hv, w[3], za2.w);
        zb2v.x = fmaf(hv, w[4], zb2v.x); zb2v.y = fmaf(hv, w[5], zb2v.y);
        zb2v.z = fmaf(hv, w[6], zb2v.z); zb2v.w = fmaf(hv, w[7], zb2v.w);
      }
      #pragma unroll
      for (int k = 0; k < U_; ++k) {
        float hv = h2[k];
        const float* w = &W2r[k * ZC + 8 * wv];
        za2.x  = fmaf(hv, w[0], za2.x);  za2.y  = fmaf(hv, w[1], za2.y);
        za2.z  = fmaf(hv, w[2], za2.z);  za2.w  = fmaf(hv, w[3], za2.w);
        zb2v.x = fmaf(hv, w[4], zb2v.x); zb2v.y = fmaf(hv, w[5], zb2v.y);
        zb2v.z = fmaf(hv, w[6], zb2v.z); zb2v.w = fmaf(hv, w[7], zb2v.w);
      }
      float* zp = &zb2[(8 * wv) * 64 + sl];
      zp[0 * 64] = za2.x;  zp[1 * 64] = za2.y;  zp[2 * 64] = za2.z;  zp[3 * 64] = za2.w;
      zp[4 * 64] = zb2v.x; zp[5 * 64] = zb2v.y; zp[6 * 64] = zb2v.z; zp[7 * 64] = zb2v.w;
    }
    __syncthreads();                                   // B3

    // ---- LSTM2 state update (replicated) ----
    #pragma unroll
    for (int u = 0; u < U_; ++u) {
      float zi = zb2[u * 64 + sl];
      float zf = zb2[(U_ + u) * 64 + sl];
      float zg = zb2[(2 * U_ + u) * 64 + sl];
      float zo = zb2[(3 * U_ + u) * 64 + sl];
      float iv = sigm(zi), fv = sigm(zf), gv = tanh_f(zg), ov = sigm(zo);
      float cn = fv * c2[u] + iv * gv;
      c2[u] = cn;
      h2[u] = ov * tanh_f(cn);
    }

    p ^= 1;
  }

  // ---- Dense(27) + softmax (redundant per wave; wave 0 stages the write) ----
  float lg[NC];
  float m = -1e30f;
  #pragma unroll
  for (int c = 0; c < NC; ++c) {
    float acc = bd[c];
    #pragma unroll
    for (int k = 0; k < U_; ++k) acc = fmaf(h2[k], Wd[k * NC + c], acc);
    lg[c] = acc;
    m = fmaxf(m, acc);
  }
  float ssum = 0.f;
  #pragma unroll
  for (int c = 0; c < NC; ++c) {
    float e = __expf(lg[c] - m);
    lg[c] = e;
    ssum += e;
  }
  float inv = 1.0f / ssum;
  if (wv == 0) {
    #pragma unroll
    for (int c = 0; c < NC; ++c) zb1[sl * NC + c] = lg[c] * inv;
  }
  __syncthreads();
  {
    float* oblk = out + (size_t)grp * 64 * NC;
    #pragma unroll
    for (int k = 0; k < 7; ++k) {
      int j = tid + k * 256;
      if (j < 64 * NC) oblk[j] = zb1[j];   // coalesced store
    }
  }
}

extern "C" void kernel_launch(void* const* d_in, const int* in_sizes, int n_in,
                              void* d_out, int out_size, void* d_ws, size_t ws_size,
                              hipStream_t stream) {
  const float* X   = (const float*)d_in[0];
  const float* W1k = (const float*)d_in[1];
  const float* W1r = (const float*)d_in[2];
  const float* b1  = (const float*)d_in[3];
  const float* W2k = (const float*)d_in[4];
  const float* W2r = (const float*)d_in[5];
  const float* b2  = (const float*)d_in[6];
  const float* Wd  = (const float*)d_in[7];
  const float* bd  = (const float*)d_in[8];
  float* out = (float*)d_out;
  (void)d_ws; (void)ws_size;   // workspace intentionally unused (fused design)

  const int B    = in_sizes[0] / ROW;   // 32768
  const int ngrp = B / 64;              // 512

  lstm_fused<<<dim3(ngrp), 256, 0, stream>>>(
      X, W1k, b1, W1r, W2k, W2r, b2, Wd, bd, out);
}

// Round 3
// 526.063 us; speedup vs baseline: 1.1085x; 1.0460x over previous
//
#include <hip/hip_runtime.h>

// ---------------------------------------------------------------------------
// FUSED 2-layer LSTM (Keras gates i,f,g,o) + Dense(27) + softmax. fp32.
// B=32768, T=21, F=126, U=8.
//
// R7: attack wave starvation (R6: occupancy 19.7% = 2 waves/SIMD, VALUBusy
// 52%, hbm 10% -> latency-bound). Split the f reduction across 2 wave
// groups: block = 512 thr = 8 waves, wave = (colgrp x fhalf). The existing
// z1 LDS exchange absorbs the f-split (sum 2 partials). Role-split the
// recurrences: fhalf0 waves own LSTM1 (h1,c1 + h1@W1r + h1@W2k), fhalf1
// waves own LSTM2 (h2,c2 + h2@W2r) -> halves replicated activation work.
// 2 barriers/t (was 3): x(t+1) LDS drain fits between Ba and Bb (all x
// reads complete before Ba), so single x buffer, no B1.
//
// Steady state per t:
//   GEMM partial z1 (fh0: +b1 +h1@W1r) -> write zb1[fh] -> Ba
//   all: drain x(t+1) regs->LDS, issue prefetch x(t+2)
//   fh0: LSTM1 (z1 = sum partials) -> h1; z2ff = b2 + h1@W2k -> zb2[0]
//   fh1: z2rec = h2@W2r -> zb2[1]
//   Bb
//   fh1: LSTM2 (z2 = sum partials) -> h2
// LDS: x 31.5K + zb1 16K + zb2 16K = 63.5 KB -> 2 blocks/CU = 4 waves/SIMD.
// ---------------------------------------------------------------------------

namespace {
constexpr int T_  = 21;
constexpr int FIN = 126;
constexpr int U_  = 8;
constexpr int NC  = 27;
constexpr int ZC  = 4 * U_;              // 32 gate columns
constexpr int ROW = T_ * FIN;            // 2646 floats per sample
constexpr int NT  = 512;                 // threads per block (8 waves)
constexpr int NPF = 8;                   // float2 staged per thread
}

__device__ __forceinline__ float sigm(float x) {
  return __builtin_amdgcn_rcpf(1.0f + __expf(-x));
}
__device__ __forceinline__ float tanh_f(float x) {
  return 1.0f - 2.0f * __builtin_amdgcn_rcpf(1.0f + __expf(2.0f * x));
}

__global__ __launch_bounds__(NT) void lstm_fused(
    const float* __restrict__ X,
    const float* __restrict__ W1k, const float* __restrict__ b1,
    const float* __restrict__ W1r,
    const float* __restrict__ W2k, const float* __restrict__ W2r,
    const float* __restrict__ b2,
    const float* __restrict__ Wd, const float* __restrict__ bd,
    float* __restrict__ out)
{
  __shared__ __align__(16) float xb[64 * FIN];        // 31.5 KB, single buffer
  // z exchanges: [col][half][sample] so the 2 partials are 64 floats apart
  // (compiler can fuse the pair into ds_read2_b32).
  __shared__ __align__(16) float zb1[ZC * 2 * 64];    // 16 KB
  __shared__ __align__(16) float zb2[ZC * 2 * 64];    // 16 KB

  const int tid = threadIdx.x;
  const int sl  = tid & 63;                                   // sample lane
  const int wv  = __builtin_amdgcn_readfirstlane(tid >> 6);   // 0..7
  const int cg  = wv & 3;        // column group: cols [8cg, 8cg+8)
  const int fh  = wv >> 2;       // f half: 0 -> q in [0,32), 1 -> q in [32,63)
  const int grp = blockIdx.x;

  // staging decomposition: j over 64*63 float2 elems, 8 per thread
  int  goff[NPF];
  int  loff[NPF];
  bool val[NPF];
  #pragma unroll
  for (int k = 0; k < NPF; ++k) {
    int j = tid + k * NT;
    val[k] = (j < 64 * 63);
    int s = j / 63;
    int q = j - s * 63;
    goff[k] = s * ROW + 2 * q;
    loff[k] = s * FIN + 2 * q;
  }

  const float* xbase = X + (size_t)grp * 64 * ROW;

  const float4* Wk4 = reinterpret_cast<const float4*>(W1k) + 2 * cg;
  // recurrent weights for this wave's role (fh0: layer1, fh1: layer2)
  const float*  Wrr = (fh == 0) ? W1r : W2r;
  const float4  b1a = reinterpret_cast<const float4*>(b1)[2 * cg];
  const float4  b1b = reinterpret_cast<const float4*>(b1)[2 * cg + 1];
  const float4  b2a = reinterpret_cast<const float4*>(b2)[2 * cg];
  const float4  b2b = reinterpret_cast<const float4*>(b2)[2 * cg + 1];

  // role-overlaid state: fh0 -> (h1,c1), fh1 -> (h2,c2)
  float hs[U_], cs[U_];
  #pragma unroll
  for (int u = 0; u < U_; ++u) { hs[u] = 0.f; cs[u] = 0.f; }

  // prologue: x(0) -> regs -> LDS; issue x(1) prefetch; barrier
  float2 pf[NPF];
  #pragma unroll
  for (int k = 0; k < NPF; ++k)
    if (val[k]) pf[k] = *reinterpret_cast<const float2*>(xbase + goff[k]);
  #pragma unroll
  for (int k = 0; k < NPF; ++k)
    if (val[k]) *reinterpret_cast<float2*>(&xb[loff[k]]) = pf[k];
  {
    const float* xt = xbase + FIN;
    #pragma unroll
    for (int k = 0; k < NPF; ++k)
      if (val[k]) pf[k] = *reinterpret_cast<const float2*>(xt + goff[k]);
  }
  __syncthreads();

  for (int t = 0; t < T_; ++t) {
    // ---- layer-1 GEMM partial over this wave's f-half ----
    float4 za, zbv;
    if (fh == 0) { za = b1a; zbv = b1b; }
    else {
      za  = make_float4(0.f, 0.f, 0.f, 0.f);
      zbv = make_float4(0.f, 0.f, 0.f, 0.f);
    }

    const float2* xr = reinterpret_cast<const float2*>(&xb[sl * FIN]);
    auto run_gemm = [&](const int q0, const int qn) {
      #pragma unroll 4
      for (int qq = 0; qq < qn; ++qq) {
        const int q = q0 + qq;
        float2 xv  = xr[q];
        float4 wa0 = Wk4[(2 * q) * 8];
        float4 wb0 = Wk4[(2 * q) * 8 + 1];
        float4 wa1 = Wk4[(2 * q + 1) * 8];
        float4 wb1 = Wk4[(2 * q + 1) * 8 + 1];
        za.x  = fmaf(xv.x, wa0.x, za.x);  za.y  = fmaf(xv.x, wa0.y, za.y);
        za.z  = fmaf(xv.x, wa0.z, za.z);  za.w  = fmaf(xv.x, wa0.w, za.w);
        zbv.x = fmaf(xv.x, wb0.x, zbv.x); zbv.y = fmaf(xv.x, wb0.y, zbv.y);
        zbv.z = fmaf(xv.x, wb0.z, zbv.z); zbv.w = fmaf(xv.x, wb0.w, zbv.w);
        za.x  = fmaf(xv.y, wa1.x, za.x);  za.y  = fmaf(xv.y, wa1.y, za.y);
        za.z  = fmaf(xv.y, wa1.z, za.z);  za.w  = fmaf(xv.y, wa1.w, za.w);
        zbv.x = fmaf(xv.y, wb1.x, zbv.x); zbv.y = fmaf(xv.y, wb1.y, zbv.y);
        zbv.z = fmaf(xv.y, wb1.z, zbv.z); zbv.w = fmaf(xv.y, wb1.w, zbv.w);
      }
    };
    if (fh == 0) run_gemm(0, 32);
    else         run_gemm(32, 31);

    // fh0 adds the layer-1 recurrent term h1(t-1) @ W1r
    if (fh == 0) {
      #pragma unroll
      for (int k = 0; k < U_; ++k) {
        float hv = hs[k];
        const float* w = &Wrr[k * ZC + 8 * cg];
        za.x  = fmaf(hv, w[0], za.x);  za.y  = fmaf(hv, w[1], za.y);
        za.z  = fmaf(hv, w[2], za.z);  za.w  = fmaf(hv, w[3], za.w);
        zbv.x = fmaf(hv, w[4], zbv.x); zbv.y = fmaf(hv, w[5], zbv.y);
        zbv.z = fmaf(hv, w[6], zbv.z); zbv.w = fmaf(hv, w[7], zbv.w);
      }
    }

    // write z1 partial: zb1[(col)*128 + fh*64 + sl]
    {
      float* zp = &zb1[(8 * cg) * 128 + fh * 64 + sl];
      zp[0 * 128] = za.x;  zp[1 * 128] = za.y;  zp[2 * 128] = za.z;  zp[3 * 128] = za.w;
      zp[4 * 128] = zbv.x; zp[5 * 128] = zbv.y; zp[6 * 128] = zbv.z; zp[7 * 128] = zbv.w;
    }
    __syncthreads();                                   // Ba: z1 visible, x reads done

    // drain x(t+1) into LDS (window Ba..Bb), issue prefetch of x(t+2)
    if (t + 1 < T_) {
      #pragma unroll
      for (int k = 0; k < NPF; ++k)
        if (val[k]) *reinterpret_cast<float2*>(&xb[loff[k]]) = pf[k];
    }
    if (t + 2 < T_) {
      const float* xt = xbase + (size_t)(t + 2) * FIN;
      #pragma unroll
      for (int k = 0; k < NPF; ++k)
        if (val[k]) pf[k] = *reinterpret_cast<const float2*>(xt + goff[k]);
    }

    if (fh == 0) {
      // ---- LSTM1 update (only fh0 waves; z1 = sum of 2 partials) ----
      #pragma unroll
      for (int u = 0; u < U_; ++u) {
        const float* p0 = &zb1[u * 128 + sl];
        float zi = p0[0]            + p0[64];
        float zf = p0[ 8 * 128]     + p0[ 8 * 128 + 64];
        float zg = p0[16 * 128]     + p0[16 * 128 + 64];
        float zo = p0[24 * 128]     + p0[24 * 128 + 64];
        float iv = sigm(zi), fv = sigm(zf), gv = tanh_f(zg), ov = sigm(zo);
        float cn = fv * cs[u] + iv * gv;
        cs[u] = cn;
        hs[u] = ov * tanh_f(cn);
      }
      // z2 feed-forward partial: b2 + h1 @ W2k (this wave's 8 cols)
      float4 za2 = b2a, zb2v = b2b;
      #pragma unroll
      for (int k = 0; k < U_; ++k) {
        float hv = hs[k];
        const float* w = &W2k[k * ZC + 8 * cg];
        za2.x  = fmaf(hv, w[0], za2.x);  za2.y  = fmaf(hv, w[1], za2.y);
        za2.z  = fmaf(hv, w[2], za2.z);  za2.w  = fmaf(hv, w[3], za2.w);
        zb2v.x = fmaf(hv, w[4], zb2v.x); zb2v.y = fmaf(hv, w[5], zb2v.y);
        zb2v.z = fmaf(hv, w[6], zb2v.z); zb2v.w = fmaf(hv, w[7], zb2v.w);
      }
      float* zp = &zb2[(8 * cg) * 128 + 0 * 64 + sl];
      zp[0 * 128] = za2.x;  zp[1 * 128] = za2.y;  zp[2 * 128] = za2.z;  zp[3 * 128] = za2.w;
      zp[4 * 128] = zb2v.x; zp[5 * 128] = zb2v.y; zp[6 * 128] = zb2v.z; zp[7 * 128] = zb2v.w;
    } else {
      // z2 recurrent partial: h2(t-1) @ W2r (this wave's 8 cols)
      float4 za2  = make_float4(0.f, 0.f, 0.f, 0.f);
      float4 zb2v = make_float4(0.f, 0.f, 0.f, 0.f);
      #pragma unroll
      for (int k = 0; k < U_; ++k) {
        float hv = hs[k];
        const float* w = &Wrr[k * ZC + 8 * cg];
        za2.x  = fmaf(hv, w[0], za2.x);  za2.y  = fmaf(hv, w[1], za2.y);
        za2.z  = fmaf(hv, w[2], za2.z);  za2.w  = fmaf(hv, w[3], za2.w);
        zb2v.x = fmaf(hv, w[4], zb2v.x); zb2v.y = fmaf(hv, w[5], zb2v.y);
        zb2v.z = fmaf(hv, w[6], zb2v.z); zb2v.w = fmaf(hv, w[7], zb2v.w);
      }
      float* zp = &zb2[(8 * cg) * 128 + 1 * 64 + sl];
      zp[0 * 128] = za2.x;  zp[1 * 128] = za2.y;  zp[2 * 128] = za2.z;  zp[3 * 128] = za2.w;
      zp[4 * 128] = zb2v.x; zp[5 * 128] = zb2v.y; zp[6 * 128] = zb2v.z; zp[7 * 128] = zb2v.w;
    }
    __syncthreads();                                   // Bb: z2 + x(t+1) visible

    if (fh == 1) {
      // ---- LSTM2 update (only fh1 waves; z2 = sum of 2 partials) ----
      #pragma unroll
      for (int u = 0; u < U_; ++u) {
        const float* p0 = &zb2[u * 128 + sl];
        float zi = p0[0]            + p0[64];
        float zf = p0[ 8 * 128]     + p0[ 8 * 128 + 64];
        float zg = p0[16 * 128]     + p0[16 * 128 + 64];
        float zo = p0[24 * 128]     + p0[24 * 128 + 64];
        float iv = sigm(zi), fv = sigm(zf), gv = tanh_f(zg), ov = sigm(zo);
        float cn = fv * cs[u] + iv * gv;
        cs[u] = cn;
        hs[u] = ov * tanh_f(cn);
      }
    }
  }

  // ---- Dense(27) + softmax: fh1 waves hold h2(T-1); wave 4 stages ----
  if (wv == 4) {
    float lg[NC];
    float m = -1e30f;
    #pragma unroll
    for (int c = 0; c < NC; ++c) {
      float acc = bd[c];
      #pragma unroll
      for (int k = 0; k < U_; ++k) acc = fmaf(hs[k], Wd[k * NC + c], acc);
      lg[c] = acc;
      m = fmaxf(m, acc);
    }
    float ssum = 0.f;
    #pragma unroll
    for (int c = 0; c < NC; ++c) {
      float e = __expf(lg[c] - m);
      lg[c] = e;
      ssum += e;
    }
    float inv = 1.0f / ssum;
    #pragma unroll
    for (int c = 0; c < NC; ++c) zb1[sl * NC + c] = lg[c] * inv;
  }
  __syncthreads();
  {
    float* oblk = out + (size_t)grp * 64 * NC;
    #pragma unroll
    for (int k = 0; k < 4; ++k) {
      int j = tid + k * NT;
      if (j < 64 * NC) oblk[j] = zb1[j];   // coalesced store
    }
  }
}

extern "C" void kernel_launch(void* const* d_in, const int* in_sizes, int n_in,
                              void* d_out, int out_size, void* d_ws, size_t ws_size,
                              hipStream_t stream) {
  const float* X   = (const float*)d_in[0];
  const float* W1k = (const float*)d_in[1];
  const float* W1r = (const float*)d_in[2];
  const float* b1  = (const float*)d_in[3];
  const float* W2k = (const float*)d_in[4];
  const float* W2r = (const float*)d_in[5];
  const float* b2  = (const float*)d_in[6];
  const float* Wd  = (const float*)d_in[7];
  const float* bd  = (const float*)d_in[8];
  float* out = (float*)d_out;
  (void)d_ws; (void)ws_size;   // workspace intentionally unused (fused design)

  const int B    = in_sizes[0] / ROW;   // 32768
  const int ngrp = B / 64;              // 512

  lstm_fused<<<dim3(ngrp), NT, 0, stream>>>(
      X, W1k, b1, W1r, W2k, W2r, b2, Wd, bd, out);
}